// Round 1
// baseline (53539.709 us; speedup 1.0000x reference)
//
#include <hip/hip_runtime.h>

#define Hh 1024
#define NBATCH 128
#define TSTEPS 256
#define DOUT 1024
#define SLOT (NBATCH * Hh)

typedef _Float16 half8 __attribute__((ext_vector_type(8)));
typedef float floatx4 __attribute__((ext_vector_type(4)));

__device__ __forceinline__ float fast_sigmoid(float x) {
  float e = __expf(-x);
  return __builtin_amdgcn_rcpf(1.0f + e);
}
__device__ __forceinline__ float fast_tanh(float x) {
  x = fminf(15.0f, fmaxf(-15.0f, x));
  float e = __expf(-2.0f * x);
  return 1.0f - 2.0f * e * __builtin_amdgcn_rcpf(1.0f + e);
}

// Convert weights to f16, build W_sum = W_ih + W_hh, b_sum = b_ih + b_hh,
// stage hT as f16 into hs slot 0, zero flags (256) + per-XCD counters (8).
__global__ void prep_kernel(const float* __restrict__ W_ih, const float* __restrict__ W_hh,
                            const float* __restrict__ W_fc, const float* __restrict__ b_ih,
                            const float* __restrict__ b_hh, const float* __restrict__ hT,
                            _Float16* __restrict__ w_ih_h, _Float16* __restrict__ w_sum_h,
                            _Float16* __restrict__ w_fc_h, float* __restrict__ b_sum,
                            _Float16* __restrict__ hs0, unsigned* __restrict__ flags) {
  int i0 = blockIdx.x * blockDim.x + threadIdx.x;
  int stride = gridDim.x * blockDim.x;
  for (int i = i0; i < 4096 * 1024; i += stride) {
    float a = W_ih[i];
    w_ih_h[i] = (_Float16)a;
    w_sum_h[i] = (_Float16)(a + W_hh[i]);
  }
  for (int i = i0; i < 1024 * 1024; i += stride) w_fc_h[i] = (_Float16)W_fc[i];
  for (int i = i0; i < 4096; i += stride) b_sum[i] = b_ih[i] + b_hh[i];
  for (int i = i0; i < NBATCH * Hh; i += stride) hs0[i] = (_Float16)hT[i];
  for (int i = i0; i < 512; i += stride) flags[i] = 0;  // flags[256] + xcd_ctr[8]
}

// Persistent LSTM kernel: 256 WGs (one per CU, forced by >256 VGPR/lane), 4 waves.
// XCD-LOCAL barrier groups: each WG reads its physical XCC_ID and self-assigns
// (group g = XCD id, j-block jb = per-XCD claim counter 0..31). Group g owns
// n-rows [16g, 16g+16); WG (g,jb) owns hidden cols [32jb, 32jb+32) x 4 gates.
// All per-step communication (h tile + flags) is therefore confined to ONE
// XCD's coherent L2:
//   - h stores are PLAIN stores (dirty local L2, fast vmcnt ack; inter-kernel
//     visibility for fc_kernel is guaranteed by the dispatch-boundary flush).
//   - flags: plain store, sc0 (L1-bypass-only) poll loads served by local L2.
//   - each wave polls only the 8 producer flags covering its K-range
//     [256w, 256w+256), so it starts as soon as ITS producers finish.
// Deadlock insurance: every 2048 spins one sc0+sc1 (coherence-point) load.
__global__ __launch_bounds__(256, 1) void lstm_kernel(
    const _Float16* __restrict__ w_ih_h, const _Float16* __restrict__ w_sum_h,
    const float* __restrict__ b_sum, _Float16* __restrict__ hs,
    unsigned* __restrict__ flags) {
  unsigned* xcd_ctr = flags + 256;
  const int tid = threadIdx.x;
  const int wave = tid >> 6;
  const int lane = tid & 63;
  const int l15 = lane & 15;
  const int quad = lane >> 4;

  __shared__ unsigned role_sh;
  {
    unsigned xcd;
    asm volatile("s_getreg_b32 %0, hwreg(HW_REG_XCC_ID)" : "=s"(xcd));
    if (tid == 0) role_sh = (xcd << 8) | atomicAdd(&xcd_ctr[xcd], 1u);
  }
  __syncthreads();
  const int g = role_sh >> 8;    // physical XCD == n-group
  const int jb = role_sh & 255;  // 0..31 within the XCD
  const int n0 = g * 16;
  const int j0 = jb * 32;
  const int kbase = wave * 256;
  const int oc = wave >> 1;  // ct half this wave reduces/owns
  const int rp = wave & 1;   // accumulator reg-pair this wave reduces/owns

  unsigned* gflags = flags + g * 32;
  const unsigned long long pollp =
      (unsigned long long)(gflags + wave * 8 + (lane & 7));

  __shared__ float2 part[4][2][4][2][64];  // [src][ct][gate][rpair][lane] = 32KB

  float bias[4];
#pragma unroll
  for (int gt = 0; gt < 4; ++gt) bias[gt] = b_sum[gt * 1024 + j0 + oc * 16 + l15];

  half8 B[4][2][8];             // 256 VGPR/AGPR of resident weights per lane
  float cst[2] = {0.0f, 0.0f};  // persistent cell state (this thread's 2 slots)

  auto load_B = [&](const _Float16* w) {
#pragma unroll
    for (int gt = 0; gt < 4; ++gt)
#pragma unroll
      for (int ct = 0; ct < 2; ++ct) {
        const _Float16* p =
            w + (size_t)(gt * 1024 + j0 + ct * 16 + l15) * Hh + kbase + quad * 8;
#pragma unroll
        for (int ks = 0; ks < 8; ++ks) B[gt][ct][ks] = *(const half8*)(p + ks * 32);
      }
  };

  auto poll = [&](int tgt) {
    int spins = 0;
    while (1) {
      unsigned v;
      asm volatile("global_load_dword %0, %1, off sc0\n\ts_waitcnt vmcnt(0)"
                   : "=v"(v) : "v"(pollp) : "memory");
      if (__all((int)(v >= (unsigned)tgt))) break;
      if (++spins > 2048) {  // insurance: periodic coherence-point read
        spins = 0;
        asm volatile("global_load_dword %0, %1, off sc0 sc1\n\ts_waitcnt vmcnt(0)"
                     : "=v"(v) : "v"(pollp) : "memory");
        if (__all((int)(v >= (unsigned)tgt))) break;
      }
    }
  };

  auto do_step = [&](const _Float16* hsrc, _Float16* hdst, int sready, bool setflag) {
    poll(sready);  // wait only for this wave's 8 producers
    floatx4 acc[2][4] = {};
    const _Float16* ap = hsrc + (size_t)(n0 + l15) * Hh + kbase + quad * 8;
#pragma unroll
    for (int ks = 0; ks < 8; ++ks) {
      half8 a = *(const half8*)(ap + ks * 32);
#pragma unroll
      for (int ct = 0; ct < 2; ++ct)
#pragma unroll
        for (int gt = 0; gt < 4; ++gt)
          acc[ct][gt] =
              __builtin_amdgcn_mfma_f32_16x16x32_f16(a, B[gt][ct][ks], acc[ct][gt], 0, 0, 0);
    }
#pragma unroll
    for (int ct = 0; ct < 2; ++ct)
#pragma unroll
      for (int gt = 0; gt < 4; ++gt) {
        float2 lo, hi;
        lo.x = acc[ct][gt][0]; lo.y = acc[ct][gt][1];
        hi.x = acc[ct][gt][2]; hi.y = acc[ct][gt][3];
        part[wave][ct][gt][0][lane] = lo;
        part[wave][ct][gt][1][lane] = hi;
      }
    __syncthreads();

    float gv[4][2];
#pragma unroll
    for (int gt = 0; gt < 4; ++gt) {
      float2 s = part[0][oc][gt][rp][lane];
#pragma unroll
      for (int src = 1; src < 4; ++src) {
        float2 p = part[src][oc][gt][rp][lane];
        s.x += p.x; s.y += p.y;
      }
      gv[gt][0] = s.x + bias[gt];
      gv[gt][1] = s.y + bias[gt];
    }
#pragma unroll
    for (int rr = 0; rr < 2; ++rr) {
      float ig = fast_sigmoid(gv[0][rr]);
      float fg = fast_sigmoid(gv[1][rr]);
      float gg = fast_tanh(gv[2][rr]);
      float og = fast_sigmoid(gv[3][rr]);
      float c = fg * cst[rr] + ig * gg;
      cst[rr] = c;
      float h = og * fast_tanh(c);
      int row = n0 + quad * 4 + rp * 2 + rr;
      // plain store: lands dirty in the XCD-local L2; consumers are same-XCD.
      hdst[(size_t)row * Hh + j0 + oc * 16 + l15] = (_Float16)h;
    }
    // barrier's vmcnt(0) drain => all 4 waves' h stores are in local L2
    // before the flag store below becomes visible (same L2 serializes).
    __syncthreads();
    if (setflag && tid == 0) gflags[jb] = (unsigned)(sready + 1);
  };

  // Step 0: x = hT, hx = 0  =>  gates = hT @ W_ih^T + b_sum
  load_B(w_ih_h);
  do_step(hs, hs + SLOT, 0, true);
  // Steps 1..255: x = hx = h  =>  gates = h @ (W_ih+W_hh)^T + b_sum
  load_B(w_sum_h);
  for (int s = 1; s < TSTEPS; ++s)
    do_step(hs + (size_t)s * SLOT, hs + (size_t)(s + 1) * SLOT, s, s < TSTEPS - 1);
}

// recons[n, s, :] = h_s @ W_fc^T + b_fc.  A = hs slots 1..256 viewed as
// [32768 x 1024] f16 (row r = s*128 + n). 64x64 tiles, 4 waves of 16 rows.
__global__ __launch_bounds__(256) void fc_kernel(const _Float16* __restrict__ A,
                                                 const _Float16* __restrict__ Bw,
                                                 const float* __restrict__ b_fc,
                                                 float* __restrict__ out) {
  const int nb = blockIdx.x;  // 0..15  (d blocks of 64)
  const int mb = blockIdx.y;  // 0..511 (row blocks of 64)
  const int tid = threadIdx.x;
  const int wave = tid >> 6;
  const int lane = tid & 63;
  const int l15 = lane & 15;
  const int quad = lane >> 4;
  const int m0 = mb * 64 + wave * 16;
  const int d0 = nb * 64;

  floatx4 acc[4] = {};
  const _Float16* ap = A + (size_t)(m0 + l15) * Hh + quad * 8;
  const _Float16* bp = Bw + (size_t)(d0 + l15) * Hh + quad * 8;
#pragma unroll 4
  for (int k = 0; k < Hh; k += 32) {
    half8 a = *(const half8*)(ap + k);
#pragma unroll
    for (int ct = 0; ct < 4; ++ct) {
      half8 b = *(const half8*)(bp + (size_t)ct * 16 * Hh + k);
      acc[ct] = __builtin_amdgcn_mfma_f32_16x16x32_f16(a, b, acc[ct], 0, 0, 0);
    }
  }
#pragma unroll
  for (int ct = 0; ct < 4; ++ct) {
    int d = d0 + ct * 16 + l15;
    float bv = b_fc[d];
#pragma unroll
    for (int r = 0; r < 4; ++r) {
      int row = m0 + quad * 4 + r;
      int s = row >> 7;
      int n = row & 127;
      out[((size_t)n * TSTEPS + s) * DOUT + d] = acc[ct][r] + bv;
    }
  }
}

extern "C" void kernel_launch(void* const* d_in, const int* in_sizes, int n_in,
                              void* d_out, int out_size, void* d_ws, size_t ws_size,
                              hipStream_t stream) {
  const float* hT   = (const float*)d_in[0];
  const float* W_ih = (const float*)d_in[1];
  const float* W_hh = (const float*)d_in[2];
  const float* b_ih = (const float*)d_in[3];
  const float* b_hh = (const float*)d_in[4];
  const float* W_fc = (const float*)d_in[5];
  const float* b_fc = (const float*)d_in[6];
  float* out = (float*)d_out;

  char* ws = (char*)d_ws;
  unsigned* flags   = (unsigned*)ws;                    // flags[256] + xcd_ctr[8]
  float* b_sum      = (float*)(ws + 4096);              // 16KB
  _Float16* w_ih_h  = (_Float16*)(ws + 65536);          // 8MB
  _Float16* w_sum_h = w_ih_h + (size_t)4096 * 1024;     // 8MB
  _Float16* w_fc_h  = w_sum_h + (size_t)4096 * 1024;    // 2MB
  _Float16* hs      = w_fc_h + (size_t)1024 * 1024;     // 257 * 256KB = 67.3MB

  prep_kernel<<<4096, 256, 0, stream>>>(W_ih, W_hh, W_fc, b_ih, b_hh, hT,
                                        w_ih_h, w_sum_h, w_fc_h, b_sum, hs, flags);
  lstm_kernel<<<256, 256, 0, stream>>>(w_ih_h, w_sum_h, b_sum, hs, flags);
  fc_kernel<<<dim3(16, 512), 256, 0, stream>>>(hs + SLOT, w_fc_h, b_fc, out);
}

// Round 2
// 1666.943 us; speedup vs baseline: 32.1185x; 32.1185x over previous
//
#include <hip/hip_runtime.h>

#define Hh 1024
#define NBATCH 128
#define TSTEPS 256
#define DOUT 1024
#define SLOT (NBATCH * Hh)

typedef _Float16 half8 __attribute__((ext_vector_type(8)));
typedef float floatx4 __attribute__((ext_vector_type(4)));

__device__ __forceinline__ float fast_sigmoid(float x) {
  float e = __expf(-x);
  return __builtin_amdgcn_rcpf(1.0f + e);
}
__device__ __forceinline__ float fast_tanh(float x) {
  x = fminf(15.0f, fmaxf(-15.0f, x));
  float e = __expf(-2.0f * x);
  return 1.0f - 2.0f * e * __builtin_amdgcn_rcpf(1.0f + e);
}

// Convert weights to f16, build W_sum = W_ih + W_hh, b_sum = b_ih + b_hh,
// stage hT as f16 into hs slot 0, zero flags (256) + per-XCD counters (8).
__global__ void prep_kernel(const float* __restrict__ W_ih, const float* __restrict__ W_hh,
                            const float* __restrict__ W_fc, const float* __restrict__ b_ih,
                            const float* __restrict__ b_hh, const float* __restrict__ hT,
                            _Float16* __restrict__ w_ih_h, _Float16* __restrict__ w_sum_h,
                            _Float16* __restrict__ w_fc_h, float* __restrict__ b_sum,
                            _Float16* __restrict__ hs0, unsigned* __restrict__ flags) {
  int i0 = blockIdx.x * blockDim.x + threadIdx.x;
  int stride = gridDim.x * blockDim.x;
  for (int i = i0; i < 4096 * 1024; i += stride) {
    float a = W_ih[i];
    w_ih_h[i] = (_Float16)a;
    w_sum_h[i] = (_Float16)(a + W_hh[i]);
  }
  for (int i = i0; i < 1024 * 1024; i += stride) w_fc_h[i] = (_Float16)W_fc[i];
  for (int i = i0; i < 4096; i += stride) b_sum[i] = b_ih[i] + b_hh[i];
  for (int i = i0; i < NBATCH * Hh; i += stride) hs0[i] = (_Float16)hT[i];
  for (int i = i0; i < 512; i += stride) flags[i] = 0;  // flags[256] + xcd_ctr[8]
}

// Persistent LSTM kernel: 256 WGs (one per CU), 4 waves each.
// XCD-LOCAL barrier groups: each WG reads its physical XCC_ID and self-assigns
// (group g = XCD id, j-block jb = per-XCD claim counter 0..31). Group g owns
// n-rows [16g, 16g+16); WG (g,jb) owns hidden cols [32jb, 32jb+32) x 4 gates.
// Per-step communication (h tile + flags) is confined to ONE XCD, shortening
// the producer->consumer path and keeping A-tile reads XCD-L2-local (v1
// evidence: FETCH_SIZE 275MB -> 98MB).
//
// Coherence ops are the v0-PROVEN set (v1's plain-store + sc0-poll combo was
// invisible to the consumer and fell back to L2-eviction timing, 30x slower):
//   - h stores: relaxed AGENT atomic store (sc0 sc1 write-through; reaches
//     the coherent point before vmcnt retires; __syncthreads drains vmcnt).
//   - flags: relaxed AGENT atomic store / relaxed AGENT atomic load (both
//     cache-bypassing -> poll loop cannot stick on a stale line).
//   - A-tile reads: plain loads. hs ring is write-once, so consumer caches
//     can never hold stale copies of addresses they haven't touched.
// Fine-grained deps: wave w polls only the 8 producer flags covering its
// K-range [256w, 256w+256), so it starts as soon as ITS producers are done.
__global__ __launch_bounds__(256, 1) void lstm_kernel(
    const _Float16* __restrict__ w_ih_h, const _Float16* __restrict__ w_sum_h,
    const float* __restrict__ b_sum, _Float16* __restrict__ hs,
    unsigned* __restrict__ flags) {
  unsigned* xcd_ctr = flags + 256;
  const int tid = threadIdx.x;
  const int wave = tid >> 6;
  const int lane = tid & 63;
  const int l15 = lane & 15;
  const int quad = lane >> 4;

  __shared__ unsigned role_sh;
  {
    unsigned xcd;
    asm volatile("s_getreg_b32 %0, hwreg(HW_REG_XCC_ID)" : "=s"(xcd));
    if (tid == 0) role_sh = (xcd << 8) | atomicAdd(&xcd_ctr[xcd], 1u);
  }
  __syncthreads();
  const int g = role_sh >> 8;    // physical XCD == n-group
  const int jb = role_sh & 255;  // 0..31 within the XCD
  const int n0 = g * 16;
  const int j0 = jb * 32;
  const int kbase = wave * 256;
  const int oc = wave >> 1;  // ct half this wave reduces/owns
  const int rp = wave & 1;   // accumulator reg-pair this wave reduces/owns

  unsigned* gflags = flags + g * 32;
  unsigned* pollp = gflags + wave * 8 + (lane & 7);

  __shared__ float2 part[4][2][4][2][64];  // [src][ct][gate][rpair][lane] = 32KB

  float bias[4];
#pragma unroll
  for (int gt = 0; gt < 4; ++gt) bias[gt] = b_sum[gt * 1024 + j0 + oc * 16 + l15];

  half8 B[4][2][8];             // 256 regs of resident weights per lane
  float cst[2] = {0.0f, 0.0f};  // persistent cell state (this thread's 2 slots)

  auto load_B = [&](const _Float16* w) {
#pragma unroll
    for (int gt = 0; gt < 4; ++gt)
#pragma unroll
      for (int ct = 0; ct < 2; ++ct) {
        const _Float16* p =
            w + (size_t)(gt * 1024 + j0 + ct * 16 + l15) * Hh + kbase + quad * 8;
#pragma unroll
        for (int ks = 0; ks < 8; ++ks) B[gt][ct][ks] = *(const half8*)(p + ks * 32);
      }
  };

  auto poll = [&](int tgt) {
    while (1) {
      unsigned v = __hip_atomic_load(pollp, __ATOMIC_RELAXED, __HIP_MEMORY_SCOPE_AGENT);
      if (__all((int)(v >= (unsigned)tgt))) break;
    }
  };

  auto do_step = [&](const _Float16* hsrc, _Float16* hdst, int sready, bool setflag) {
    poll(sready);  // wait only for this wave's 8 producers
    floatx4 acc[2][4] = {};
    const _Float16* ap = hsrc + (size_t)(n0 + l15) * Hh + kbase + quad * 8;
#pragma unroll
    for (int ks = 0; ks < 8; ++ks) {
      half8 a = *(const half8*)(ap + ks * 32);
#pragma unroll
      for (int ct = 0; ct < 2; ++ct)
#pragma unroll
        for (int gt = 0; gt < 4; ++gt)
          acc[ct][gt] =
              __builtin_amdgcn_mfma_f32_16x16x32_f16(a, B[gt][ct][ks], acc[ct][gt], 0, 0, 0);
    }
#pragma unroll
    for (int ct = 0; ct < 2; ++ct)
#pragma unroll
      for (int gt = 0; gt < 4; ++gt) {
        float2 lo, hi;
        lo.x = acc[ct][gt][0]; lo.y = acc[ct][gt][1];
        hi.x = acc[ct][gt][2]; hi.y = acc[ct][gt][3];
        part[wave][ct][gt][0][lane] = lo;
        part[wave][ct][gt][1][lane] = hi;
      }
    __syncthreads();

    float gv[4][2];
#pragma unroll
    for (int gt = 0; gt < 4; ++gt) {
      float2 s = part[0][oc][gt][rp][lane];
#pragma unroll
      for (int src = 1; src < 4; ++src) {
        float2 p = part[src][oc][gt][rp][lane];
        s.x += p.x; s.y += p.y;
      }
      gv[gt][0] = s.x + bias[gt];
      gv[gt][1] = s.y + bias[gt];
    }
#pragma unroll
    for (int rr = 0; rr < 2; ++rr) {
      float ig = fast_sigmoid(gv[0][rr]);
      float fg = fast_sigmoid(gv[1][rr]);
      float gg = fast_tanh(gv[2][rr]);
      float og = fast_sigmoid(gv[3][rr]);
      float c = fg * cst[rr] + ig * gg;
      cst[rr] = c;
      float h = og * fast_tanh(c);
      int row = n0 + quad * 4 + rp * 2 + rr;
      _Float16 hv = (_Float16)h;
      unsigned short ub;
      __builtin_memcpy(&ub, &hv, 2);
      // sc1 write-through store: visible at the coherent point once vmcnt
      // retires; no dirty L2 line left behind.
      __hip_atomic_store((unsigned short*)(hdst + (size_t)row * Hh + j0 + oc * 16 + l15),
                         ub, __ATOMIC_RELAXED, __HIP_MEMORY_SCOPE_AGENT);
    }
    // Drains vmcnt(0) (h stores reach coherent point) + protects LDS reuse.
    __syncthreads();
    if (setflag && tid == 0) {
      __hip_atomic_store(&gflags[jb], (unsigned)(sready + 1), __ATOMIC_RELAXED,
                         __HIP_MEMORY_SCOPE_AGENT);
    }
  };

  // Step 0: x = hT, hx = 0  =>  gates = hT @ W_ih^T + b_sum
  load_B(w_ih_h);
  do_step(hs, hs + SLOT, 0, true);
  // Steps 1..255: x = hx = h  =>  gates = h @ (W_ih+W_hh)^T + b_sum
  load_B(w_sum_h);
  for (int s = 1; s < TSTEPS; ++s)
    do_step(hs + (size_t)s * SLOT, hs + (size_t)(s + 1) * SLOT, s, s < TSTEPS - 1);
}

// recons[n, s, :] = h_s @ W_fc^T + b_fc.  A = hs slots 1..256 viewed as
// [32768 x 1024] f16 (row r = s*128 + n). 64x64 tiles, 4 waves of 16 rows.
__global__ __launch_bounds__(256) void fc_kernel(const _Float16* __restrict__ A,
                                                 const _Float16* __restrict__ Bw,
                                                 const float* __restrict__ b_fc,
                                                 float* __restrict__ out) {
  const int nb = blockIdx.x;  // 0..15  (d blocks of 64)
  const int mb = blockIdx.y;  // 0..511 (row blocks of 64)
  const int tid = threadIdx.x;
  const int wave = tid >> 6;
  const int lane = tid & 63;
  const int l15 = lane & 15;
  const int quad = lane >> 4;
  const int m0 = mb * 64 + wave * 16;
  const int d0 = nb * 64;

  floatx4 acc[4] = {};
  const _Float16* ap = A + (size_t)(m0 + l15) * Hh + quad * 8;
  const _Float16* bp = Bw + (size_t)(d0 + l15) * Hh + quad * 8;
#pragma unroll 4
  for (int k = 0; k < Hh; k += 32) {
    half8 a = *(const half8*)(ap + k);
#pragma unroll
    for (int ct = 0; ct < 4; ++ct) {
      half8 b = *(const half8*)(bp + (size_t)ct * 16 * Hh + k);
      acc[ct] = __builtin_amdgcn_mfma_f32_16x16x32_f16(a, b, acc[ct], 0, 0, 0);
    }
  }
#pragma unroll
  for (int ct = 0; ct < 4; ++ct) {
    int d = d0 + ct * 16 + l15;
    float bv = b_fc[d];
#pragma unroll
    for (int r = 0; r < 4; ++r) {
      int row = m0 + quad * 4 + r;
      int s = row >> 7;
      int n = row & 127;
      out[((size_t)n * TSTEPS + s) * DOUT + d] = acc[ct][r] + bv;
    }
  }
}

extern "C" void kernel_launch(void* const* d_in, const int* in_sizes, int n_in,
                              void* d_out, int out_size, void* d_ws, size_t ws_size,
                              hipStream_t stream) {
  const float* hT   = (const float*)d_in[0];
  const float* W_ih = (const float*)d_in[1];
  const float* W_hh = (const float*)d_in[2];
  const float* b_ih = (const float*)d_in[3];
  const float* b_hh = (const float*)d_in[4];
  const float* W_fc = (const float*)d_in[5];
  const float* b_fc = (const float*)d_in[6];
  float* out = (float*)d_out;

  char* ws = (char*)d_ws;
  unsigned* flags   = (unsigned*)ws;                    // flags[256] + xcd_ctr[8]
  float* b_sum      = (float*)(ws + 4096);              // 16KB
  _Float16* w_ih_h  = (_Float16*)(ws + 65536);          // 8MB
  _Float16* w_sum_h = w_ih_h + (size_t)4096 * 1024;     // 8MB
  _Float16* w_fc_h  = w_sum_h + (size_t)4096 * 1024;    // 2MB
  _Float16* hs      = w_fc_h + (size_t)1024 * 1024;     // 257 * 256KB = 67.3MB

  prep_kernel<<<4096, 256, 0, stream>>>(W_ih, W_hh, W_fc, b_ih, b_hh, hT,
                                        w_ih_h, w_sum_h, w_fc_h, b_sum, hs, flags);
  lstm_kernel<<<256, 256, 0, stream>>>(w_ih_h, w_sum_h, b_sum, hs, flags);
  fc_kernel<<<dim3(16, 512), 256, 0, stream>>>(hs + SLOT, w_fc_h, b_fc, out);
}